// Round 5
// baseline (2633.606 us; speedup 1.0000x reference)
//
#include <hip/hip_runtime.h>
#include <math.h>

typedef short short8 __attribute__((ext_vector_type(8)));
typedef float f32x4 __attribute__((ext_vector_type(4)));
typedef unsigned short u16;
typedef unsigned int u32;

#define GAS(p) ((__attribute__((address_space(1))) void*)(p))
#define LAS(p) ((__attribute__((address_space(3))) void*)(p))

namespace {

constexpr int HW   = 1440;           // 18*80
constexpr int PBAT = 20 * 82 * 1024; // padded per-batch elems

__device__ __forceinline__ u16 f2bf(float f) {
  u32 u = __float_as_uint(f);
  return (u16)((u + 0x7FFFu + ((u >> 16) & 1u)) >> 16);
}
__device__ __forceinline__ float bf2f(u16 h) {
  return __uint_as_float(((u32)h) << 16);
}

// XCD-aware bijective remap (m204 variant): dispatch id -> virt, where each of
// the 8 XCDs (id%8 under round-robin dispatch) owns a CONTIGUOUS virt range.
// virt enumerated oy-major (virt/gx = oy) => each XCD keeps ~1 weight panel
// (2.36 MB) resident in its 4 MB L2 instead of cycling through all of them.
__device__ __forceinline__ int xcd_virt(int id, int N) {
  int q = N >> 3, r = N & 7;
  int xcd = id & 7, pos = id >> 3;
  return (xcd < r ? xcd * (q + 1) : r * (q + 1) + (xcd - r) * q) + pos;
}

// ---------------- NCHW fp32 -> padded NHWC bf16 ----------------
__global__ __launch_bounds__(256)
void transpose_feat(const float* __restrict__ src, u16* __restrict__ dst) {
  __shared__ float tile[128][17];
  const int bh = blockIdx.y;            // 0..143
  const int b = bh / 18, h = bh % 18;
  const int wt = blockIdx.x % 5, ct = blockIdx.x / 5;
  const int w0 = wt * 16, c0 = ct * 128;
  const int tid = threadIdx.x;
#pragma unroll
  for (int it = 0; it < 8; ++it) {
    int idx = it * 256 + tid;
    int c = idx >> 4, w = idx & 15;
    tile[c][w] = src[((size_t)(b * 1024 + c0 + c) * 18 + h) * 80 + w0 + w];
  }
  __syncthreads();
  const int px = tid >> 4, cq = tid & 15;
  union { uint4 u; u16 s[8]; } pk;
#pragma unroll
  for (int j = 0; j < 8; ++j) pk.s[j] = f2bf(tile[cq * 8 + j][px]);
  *(uint4*)(dst + ((size_t)(b * 20 + h + 1) * 82 + (w0 + px + 1)) * 1024 + c0 + cq * 8) = pk.u;
}

// ---------------- merged weight repack: 7 tensors in one dispatch ----------------
struct RepackArgs {
  const float* src[7];
  u16* dst[7];
  int O[7];
  int start[7];
  int nseg;
};

__global__ __launch_bounds__(256)
void repack_all(RepackArgs ra) {
  int blk = blockIdx.x;
  int seg = 0;
#pragma unroll
  for (int i = 1; i < 7; ++i)
    if (i < ra.nseg && blk >= ra.start[i]) seg = i;
  const float* src = ra.src[seg];
  u16* dst = ra.dst[seg];
  const int O = ra.O[seg];
  int idx = (blk - ra.start[seg]) * 256 + threadIdx.x;
  if (idx >= O * 128) return;
  int o = idx >> 7, c8 = idx & 127;
  const float* s = src + (size_t)o * 9216 + (size_t)c8 * 72;
  float v[72];
#pragma unroll
  for (int i = 0; i < 18; ++i) {
    float4 f = *(const float4*)(s + i * 4);
    v[i * 4 + 0] = f.x; v[i * 4 + 1] = f.y; v[i * 4 + 2] = f.z; v[i * 4 + 3] = f.w;
  }
#pragma unroll
  for (int t = 0; t < 9; ++t) {
    union { uint4 u; u16 h[8]; } pk;
#pragma unroll
    for (int j = 0; j < 8; ++j) pk.h[j] = f2bf(v[j * 9 + t]);
    *(uint4*)(dst + ((size_t)t * O + o) * 1024 + c8 * 8) = pk.u;
  }
}

// ---------------- deformable bilinear sampling (device body) ----------------
__device__ __forceinline__
void sample_body(int k, int lp, int pix0, int Npc,
                 const u16* __restrict__ featP, const float* __restrict__ offp,
                 u16* __restrict__ spl, int tid) {
  const int p = pix0 + lp;
  const int c8 = tid & 15;
  int b = p / HW, hw = p - b * HW;
  int h = hw / 80, w = hw - h * 80;
  float dy = offp[p * 27 + k];
  float dx = offp[p * 27 + 9 + k];
  float ml = offp[p * 27 + 18 + k];
  float m = 1.f / (1.f + expf(-ml));
  float py = (float)(h - 1 + k / 3) + dy;
  float px = (float)(w - 1 + (k % 3)) + dx;
  float y0f = floorf(py), x0f = floorf(px);
  float wy1 = py - y0f, wx1 = px - x0f;
  float wy0 = 1.f - wy1, wx0 = 1.f - wx1;
  int y0 = (int)y0f, x0 = (int)x0f;
  int ya = min(max(y0, -1), 18),  yb = min(max(y0 + 1, -1), 18);
  int xa = min(max(x0, -1), 80),  xb = min(max(x0 + 1, -1), 80);
  const u16* base = featP + (size_t)b * PBAT;
  const u16* r00 = base + ((size_t)(ya + 1) * 82 + (xa + 1)) * 1024;
  const u16* r01 = base + ((size_t)(ya + 1) * 82 + (xb + 1)) * 1024;
  const u16* r10 = base + ((size_t)(yb + 1) * 82 + (xa + 1)) * 1024;
  const u16* r11 = base + ((size_t)(yb + 1) * 82 + (xb + 1)) * 1024;
  float w00 = wy0 * wx0 * m, w01 = wy0 * wx1 * m;
  float w10 = wy1 * wx0 * m, w11 = wy1 * wx1 * m;
  u16* dst = spl + ((size_t)k * Npc + lp) * 1024;
  for (int c = c8 * 8; c < 1024; c += 128) {
    union { uint4 u; u16 h[8]; } a, bq, cq2, d, o;
    a.u   = *(const uint4*)(r00 + c);
    bq.u  = *(const uint4*)(r01 + c);
    cq2.u = *(const uint4*)(r10 + c);
    d.u   = *(const uint4*)(r11 + c);
#pragma unroll
    for (int j = 0; j < 8; ++j) {
      float v = w00 * bf2f(a.h[j]) + w01 * bf2f(bq.h[j]) +
                w10 * bf2f(cq2.h[j]) + w11 * bf2f(d.h[j]);
      o.h[j] = f2bf(v);
    }
    *(uint4*)(dst + c) = o.u;
  }
}

__global__ __launch_bounds__(256)
void sample_standalone(const u16* __restrict__ featP, const float* __restrict__ offp,
                       u16* __restrict__ spl, int pix0, int Npc) {
  sample_body(blockIdx.y, blockIdx.x * 16 + (threadIdx.x >> 4), pix0, Npc,
              featP, offp, spl, threadIdx.x);
}

// FLAGS: 1 = planes-B, 2 = store fp32 flat [p][Co], 4 = BN, 8 = ReLU
struct Job {
  const u16* W; const u16* B;
  const float* bias; const float* bng; const float* bnb;
  void* out; int Co; int pix0; int Npc;
};

// LDS: one shared 49152-B block per kernel, passed in (avoids per-instantiation
// duplication: two inlined gemm_body copies would double static LDS).
constexpr int LDSU16 = 24576;  // 49152 bytes: As = lds[0..12288), Bs = lds[12288..24576)

// ---------------- 128x128 MFMA body, depth-2 stage-ahead pipeline ----------------
// 3 buffers each for A and B (3*8KB*2 = 48 KB total).
// Per K-step (BK=32): stage k+2, compute k, s_waitcnt vmcnt(4) (drain k+1's
// 4 loads, keep k+2's in flight), one barrier.
template<int FLAGS>
__device__ __forceinline__ void gemm_body(const Job J, u16* lds, int px, int oy) {
  constexpr bool PLANES  = (FLAGS & 1) != 0;
  constexpr bool F32OUT  = (FLAGS & 2) != 0;
  constexpr bool HASBN   = (FLAGS & 4) != 0;
  constexpr bool HASRELU = (FLAGS & 8) != 0;

  u16* As = lds;
  u16* Bs = lds + 12288;
  const int tid = threadIdx.x;
  const int wv = tid >> 6, lane = tid & 63;
  const int o0 = oy * 128;
  const int p0 = J.pix0 + px * 128;

  // staging offsets (identical swizzle to verified baseline body)
  const int lr = lane >> 2;
  const int qs = (lane & 3) ^ ((lane >> 3) & 3);
  int aoff[2], boff[2];
#pragma unroll
  for (int s = 0; s < 2; ++s) {
    int r = (wv * 2 + s) * 16 + lr;
    int o = min(o0 + r, J.Co - 1);
    aoff[s] = o * 1024 + qs * 8;
    int p = p0 + r;
    if (PLANES) {
      boff[s] = (p - J.pix0) * 1024 + qs * 8;
    } else {
      int b = p / HW, hw = p - b * HW;
      int h = hw / 80, w = hw - h * 80;
      boff[s] = ((b * 20 + h) * 82 + w) * 1024 + qs * 8;
    }
  }

  const int wm = wv >> 1, wn = wv & 1;
  const int frm = lane & 15;
  const int kq = lane >> 4;
  const int sel = (kq ^ ((lane >> 1) & 3)) * 16;

  f32x4 acc[4][4];
#pragma unroll
  for (int i = 0; i < 4; ++i)
#pragma unroll
    for (int j = 0; j < 4; ++j) acc[i][j] = (f32x4)0.f;

  // stage K-step KK (tap = KK/32, 32-ch slab) into buffer ST
#define GB_STAGE(ST, KK)                                                      \
  { int t_ = (KK) >> 5, c0_ = ((KK) & 31) << 5;                               \
    const u16* Wt_ = J.W + (size_t)t_ * (size_t)J.Co * 1024 + c0_;            \
    const u16* Bt_ = J.B + (PLANES ? (size_t)t_ * (size_t)J.Npc * 1024        \
                     : (size_t)(((t_ / 3) * 82 + (t_ % 3)) * 1024)) + c0_;    \
    u16* aD_ = As + (ST) * 4096 + (wv * 2) * 512;                             \
    u16* bD_ = Bs + (ST) * 4096 + (wv * 2) * 512;                             \
    __builtin_amdgcn_global_load_lds(GAS(Wt_ + aoff[0]), LAS(aD_),       16, 0, 0); \
    __builtin_amdgcn_global_load_lds(GAS(Wt_ + aoff[1]), LAS(aD_ + 512), 16, 0, 0); \
    __builtin_amdgcn_global_load_lds(GAS(Bt_ + boff[0]), LAS(bD_),       16, 0, 0); \
    __builtin_amdgcn_global_load_lds(GAS(Bt_ + boff[1]), LAS(bD_ + 512), 16, 0, 0); }

#define GB_MMA(ST)                                                            \
  { const char* Ab_ = (const char*)As + (ST) * 8192;                          \
    const char* Bb_ = (const char*)Bs + (ST) * 8192;                          \
    uint4 af[4], bf4[4];                                                      \
    _Pragma("unroll") for (int i_ = 0; i_ < 4; ++i_) {                        \
      af[i_]  = *(const uint4*)(Ab_ + (wm * 64 + i_ * 16 + frm) * 64 + sel);  \
      bf4[i_] = *(const uint4*)(Bb_ + (wn * 64 + i_ * 16 + frm) * 64 + sel); }\
    _Pragma("unroll") for (int i_ = 0; i_ < 4; ++i_) {                        \
      short8 a_ = __builtin_bit_cast(short8, af[i_]);                         \
      _Pragma("unroll") for (int j_ = 0; j_ < 4; ++j_) {                      \
        short8 b_ = __builtin_bit_cast(short8, bf4[j_]);                      \
        acc[i_][j_] = __builtin_amdgcn_mfma_f32_16x16x32_bf16(a_, b_, acc[i_][j_], 0, 0, 0); } } }

  // step: optionally stage KS into buffer NB, compute buffer ST, counted wait, barrier
#define GB_STEP(ST, NB, KS, DOST, VMN)                                        \
  { if (DOST) GB_STAGE(NB, KS)                                                \
    GB_MMA(ST)                                                                \
    asm volatile("s_waitcnt vmcnt(" #VMN ")" ::: "memory");                   \
    __builtin_amdgcn_s_barrier();                                             \
    asm volatile("" ::: "memory"); }

  // prologue: stage k=0 and k=1, wait for k=0 only
  GB_STAGE(0, 0)
  GB_STAGE(1, 1)
  asm volatile("s_waitcnt vmcnt(4)" ::: "memory");
  __builtin_amdgcn_s_barrier();
  asm volatile("" ::: "memory");

  // main loop: kk = 0..284 (always stages kk+2 <= 286)
  for (int i = 0; i < 95; ++i) {
    const int kk = i * 3;
    GB_STEP(0, 2, kk + 2, true, 4)
    GB_STEP(1, 0, kk + 3, true, 4)
    GB_STEP(2, 1, kk + 4, true, 4)
  }
  // tail: kk = 285 (stages 287), 286, 287
  GB_STEP(0, 2, 287, true, 4)
  GB_STEP(1, 0, 0, false, 0)
  GB_MMA(2)

#undef GB_STAGE
#undef GB_MMA
#undef GB_STEP

  size_t obase[4];
#pragma unroll
  for (int j = 0; j < 4; ++j) {
    int pn = p0 + wn * 64 + j * 16 + frm;
    if (F32OUT) {
      obase[j] = (size_t)pn * J.Co;
    } else {
      int b = pn / HW, hw = pn - b * HW;
      int h = hw / 80, w = hw - h * 80;
      obase[j] = ((size_t)(b * 20 + h + 1) * 82 + (w + 1)) * 1024;
    }
  }
#pragma unroll
  for (int i = 0; i < 4; ++i) {
    int o = o0 + wm * 64 + i * 16 + kq * 4;
    float bi[4], sc[4], sh[4];
#pragma unroll
    for (int r = 0; r < 4; ++r) {
      int oc = min(o + r, J.Co - 1);
      bi[r] = J.bias[oc];
      if (HASBN) { sc[r] = J.bng[oc] * rsqrtf(1.f + 1e-5f); sh[r] = J.bnb[oc]; }
    }
#pragma unroll
    for (int j = 0; j < 4; ++j) {
      float v[4];
#pragma unroll
      for (int r = 0; r < 4; ++r) {
        float x = acc[i][j][r] + bi[r];
        if (HASBN) x = x * sc[r] + sh[r];
        if (HASRELU) x = fmaxf(x, 0.f);
        v[r] = x;
      }
      if (F32OUT) {
        float* op = (float*)J.out;
#pragma unroll
        for (int r = 0; r < 4; ++r)
          if (o + r < J.Co) op[obase[j] + o + r] = v[r];
      } else {
        u16* op = (u16*)J.out;
        ushort4 pk;
        pk.x = f2bf(v[0]); pk.y = f2bf(v[1]); pk.z = f2bf(v[2]); pk.w = f2bf(v[3]);
        *(ushort4*)(op + obase[j] + o) = pk;
      }
    }
  }
}

template<int F0, int F1>
__global__ __launch_bounds__(256)
void gemm_dual(Job j0, Job j1, int ysplit) {
  __shared__ __align__(16) u16 lds[LDSU16];
  // XCD remap over the whole flattened grid (dispatch id is x-fastest)
  int id = blockIdx.y * gridDim.x + blockIdx.x;
  int virt = xcd_virt(id, gridDim.x * gridDim.y);
  int px = virt % gridDim.x, y = virt / gridDim.x;
  if (y < ysplit) gemm_body<F0>(j0, lds, px, y);
  else            gemm_body<F1>(j1, lds, px, y - ysplit);
}

// GEMM job co-scheduled with sampler blocks (16 px each). grid.x = n0 + 9*(nps/16).
template<int F0>
__global__ __launch_bounds__(256)
void gemm_sample(Job j, const u16* __restrict__ featP, const float* __restrict__ offp,
                 u16* __restrict__ spl, int n0, int pix0s, int nps) {
  __shared__ __align__(16) u16 lds[LDSU16];
  int gx = blockIdx.x;
  if (gx < n0) {
    int virt = xcd_virt(gx, n0);           // n0=720: XCD k <-> oy k exactly
    gemm_body<F0>(j, lds, virt % 90, virt / 90);
  } else {
    int sidx = gx - n0;
    int per = nps >> 4;
    int k = sidx / per, bs = sidx % per;
    sample_body(k, bs * 16 + ((int)threadIdx.x >> 4), pix0s, nps,
                featP, offp, spl, (int)threadIdx.x);
  }
}

// dcn chunk kernel: [n0: dcn gemm blocks][n1: cls3 head blocks][rest: sampler chunk t+1]
template<int F0, int F1>
__global__ __launch_bounds__(256)
void dcn_chunk(Job j0, Job j1, int n0, int nt0, int n1,
               const u16* __restrict__ featP, const float* __restrict__ offp,
               u16* __restrict__ splNext, int pix0n, int npn) {
  __shared__ __align__(16) u16 lds[LDSU16];
  int x = blockIdx.x;
  if (x < n0) {
    int virt = xcd_virt(x, n0);            // oy-major: virt/nt0 = oy slab per XCD
    gemm_body<F0>(j0, lds, virt % nt0, virt / nt0);
    return;
  }
  x -= n0;
  if (x < n1) { gemm_body<F1>(j1, lds, x % 90, x / 90); return; }
  x -= n1;
  int per = npn >> 4;                 // sampler blocks per tap (16 px each)
  int k = x / per, bs = x % per;
  sample_body(k, bs * 16 + ((int)threadIdx.x >> 4), pix0n, npn,
              featP, offp, splNext, (int)threadIdx.x);
}

} // namespace

extern "C" void kernel_launch(void* const* d_in, const int* in_sizes, int n_in,
                              void* d_out, int out_size, void* d_ws, size_t ws_size,
                              hipStream_t stream) {
  const float* feat   = (const float*)d_in[0];
  const float* cls_w1 = (const float*)d_in[1];
  const float* cls_b1 = (const float*)d_in[2];
  const float* cls_w2 = (const float*)d_in[3];
  const float* cls_b2 = (const float*)d_in[4];
  const float* cls_w3 = (const float*)d_in[5];
  const float* cls_b3 = (const float*)d_in[6];
  const float* off_w  = (const float*)d_in[7];
  const float* off_b  = (const float*)d_in[8];
  const float* dcn_w  = (const float*)d_in[9];
  const float* dcn_b  = (const float*)d_in[10];
  const float* bn1_g  = (const float*)d_in[11];
  const float* bn1_b  = (const float*)d_in[12];
  const float* reg_w2 = (const float*)d_in[13];
  const float* reg_b2 = (const float*)d_in[14];
  const float* bn2_g  = (const float*)d_in[15];
  const float* bn2_b  = (const float*)d_in[16];
  const float* reg_w3 = (const float*)d_in[17];
  const float* reg_b3 = (const float*)d_in[18];
  float* outp = (float*)d_out;

  const size_t ACTB = 26869760;                // 8*20*82*1024*2 bytes
  char* wsb = (char*)d_ws;
  u16* featP = (u16*)(wsb);
  u16* bufA  = (u16*)(wsb + ACTB);
  u16* bufB  = (u16*)(wsb + 2 * ACTB);
  u16* wts   = (u16*)(wsb + 3 * ACTB);
  float* offp = (float*)(wsb + 3 * ACTB + 85432320);
  u16* spl   = (u16*)(wsb + 3 * ACTB + 85432320 + 1244160);
  const size_t BASE = 3 * ACTB + 85432320 + 1244160;   // 167,285,760
  const size_t SPLB = (size_t)9 * 11520 * 1024 * 2;    // 212,336,640

  u16* offT = wts;
  u16* w1T  = wts + 248832;
  u16* w2T  = wts + 9686016;
  u16* w3T  = wts + 19123200;
  u16* dcnT = wts + 20007936;
  u16* r2T  = wts + 29445120;
  u16* r3T  = wts + 38882304;

  dim3 blk(256);

  hipMemsetAsync(featP, 0, 3 * ACTB, stream);
  transpose_feat<<<dim3(40, 144), blk, 0, stream>>>(feat, featP);

  {
    RepackArgs ra;
    const float* s[7] = {off_w, cls_w1, cls_w2, cls_w3, dcn_w, reg_w2, reg_w3};
    u16* d[7] = {offT, w1T, w2T, w3T, dcnT, r2T, r3T};
    int  O[7] = {27, 1024, 1024, 96, 1024, 1024, 416};
    int acc = 0;
    for (int i = 0; i < 7; ++i) {
      ra.src[i] = s[i]; ra.dst[i] = d[i]; ra.O[i] = O[i]; ra.start[i] = acc;
      acc += (O[i] * 128 + 255) / 256;
    }
    ra.nseg = 7;
    repack_all<<<dim3(acc), blk, 0, stream>>>(ra);
  }

  Job jOff  = {offT, featP, off_b, nullptr, nullptr, offp, 27, 0, 0};
  Job jCls1 = {w1T, featP, cls_b1, nullptr, nullptr, bufA, 1024, 0, 0};
  Job jCls2 = {w2T, bufA, cls_b2, nullptr, nullptr, bufB, 1024, 0, 0};
  Job jCls3 = {w3T, bufB, cls_b3, nullptr, nullptr, outp, 96, 0, 0};
  Job jReg2 = {r2T, bufA, reg_b2, bn2_g, bn2_b, bufB, 1024, 0, 0};
  Job jReg3 = {r3T, bufB, reg_b3, nullptr, nullptr, outp + 1105920, 416, 0, 0};

  size_t avail = ws_size > BASE ? ws_size - BASE : 0;

  // pick chunk size (in 128-px tiles) for ping-pong sampling; 0 = doesn't fit
  int tch = 0;
  {
    const int cand[5] = {30, 18, 15, 10, 9};
    for (int i = 0; i < 5; ++i)
      if ((size_t)2 * cand[i] * 2359296 <= avail) { tch = cand[i]; break; }
  }

  // D2: cls1 (relu->bf16, y<8) + offset conv (f32 flat, y==8)
  gemm_dual<8, 2><<<dim3(90, 9), blk, 0, stream>>>(jCls1, jOff, 8);

  if (avail >= SPLB) {
    // ---- tier 1: full spl fits ----
    gemm_sample<8><<<dim3(720 + 6480), blk, 0, stream>>>(jCls2, featP, offp, spl, 720, 0, 11520);
    Job jDcn = {dcnT, spl, dcn_b, bn1_g, bn1_b, bufA, 1024, 0, 11520};
    gemm_dual<1 | 4 | 8, 2><<<dim3(90, 9), blk, 0, stream>>>(jDcn, jCls3, 8);
    gemm_dual<4 | 8, 4 | 8><<<dim3(90, 8), blk, 0, stream>>>(jReg2, jReg2, 8);
    gemm_dual<2, 2><<<dim3(90, 4), blk, 0, stream>>>(jReg3, jReg3, 4);
  } else if (tch > 0) {
    // ---- tier 2: chunked ping-pong sampling ----
    const int C = 90 / tch;
    const int np = tch * 128;
    u16* splA = spl;
    u16* splB = spl + (size_t)tch * 1179648;   // elements

    // D3: cls2 (720) + sample chunk0 -> splA
    gemm_sample<8><<<dim3(720 + 9 * (np / 16)), blk, 0, stream>>>(
        jCls2, featP, offp, splA, 720, 0, np);
    // chunk loop: dcn chunk i (+cls3 in chunk0) + sample chunk i+1
    for (int i = 0; i < C; ++i) {
      u16* sCur  = (i & 1) ? splB : splA;
      u16* sNext = (i & 1) ? splA : splB;
      Job jDcnC = {dcnT, sCur, dcn_b, bn1_g, bn1_b, bufA, 1024, i * np, np};
      int n0 = tch * 8;
      int n1 = (i == 0) ? 90 : 0;
      bool hasS = (i + 1 < C);
      int ns = hasS ? 9 * (np / 16) : 0;
      dcn_chunk<1 | 4 | 8, 2><<<dim3(n0 + n1 + ns), blk, 0, stream>>>(
          jDcnC, jCls3, n0, tch, n1,
          featP, offp, sNext, (i + 1) * np, hasS ? np : 16);
    }
    gemm_dual<4 | 8, 4 | 8><<<dim3(90, 8), blk, 0, stream>>>(jReg2, jReg2, 8);
    gemm_dual<2, 2><<<dim3(90, 4), blk, 0, stream>>>(jReg3, jReg3, 4);
  } else {
    // ---- tier 3: serial chunked fallback ----
    gemm_dual<8, 8><<<dim3(90, 8), blk, 0, stream>>>(jCls2, jCls2, 8);
    int tiles = (int)(avail / 2359296);
    if (tiles < 1) tiles = 1;
    if (tiles > 90) tiles = 90;
    for (int t0 = 0; t0 < 90; t0 += tiles) {
      int nt = (90 - t0) < tiles ? (90 - t0) : tiles;
      int pix0 = t0 * 128, npp = nt * 128;
      sample_standalone<<<dim3(nt * 8, 9), blk, 0, stream>>>(featP, offp, spl, pix0, npp);
      Job jDcn = {dcnT, spl, dcn_b, bn1_g, bn1_b, bufA, 1024, pix0, npp};
      gemm_dual<1 | 4 | 8, 1 | 4 | 8><<<dim3(nt, 8), blk, 0, stream>>>(jDcn, jDcn, 8);
    }
    gemm_dual<2, 2><<<dim3(90, 1), blk, 0, stream>>>(jCls3, jCls3, 1);
    gemm_dual<4 | 8, 4 | 8><<<dim3(90, 8), blk, 0, stream>>>(jReg2, jReg2, 8);
    gemm_dual<2, 2><<<dim3(90, 4), blk, 0, stream>>>(jReg3, jReg3, 4);
  }
}

// Round 6
// 2096.287 us; speedup vs baseline: 1.2563x; 1.2563x over previous
//
#include <hip/hip_runtime.h>
#include <math.h>

typedef short short8 __attribute__((ext_vector_type(8)));
typedef float f32x4 __attribute__((ext_vector_type(4)));
typedef unsigned short u16;
typedef unsigned int u32;

#define GAS(p) ((__attribute__((address_space(1))) void*)(p))
#define LAS(p) ((__attribute__((address_space(3))) void*)(p))

namespace {

constexpr int HW   = 1440;           // 18*80
constexpr int PBAT = 20 * 82 * 1024; // padded per-batch elems

__device__ __forceinline__ u16 f2bf(float f) {
  u32 u = __float_as_uint(f);
  return (u16)((u + 0x7FFFu + ((u >> 16) & 1u)) >> 16);
}
__device__ __forceinline__ float bf2f(u16 h) {
  return __uint_as_float(((u32)h) << 16);
}

// XCD-aware bijective remap (m204): dispatch id -> virt; each of 8 XCDs
// (id%8 under round-robin) owns a CONTIGUOUS virt range. Caller decodes virt
// PX-MAJOR (px = virt/NY, oy = virt%NY) so an XCD gets a contiguous px range
// with ALL oy: the 9 B-panel sharers (same px, diff oy) are co-XCD => B
// fetched ~once. Weights stream 8x but the drain-per-K-step body keeps blocks
// K-synchronized so the live weight slab per XCD is tiny.
__device__ __forceinline__ int xcd_virt(int id, int N) {
  int q = N >> 3, r = N & 7;
  int xcd = id & 7, pos = id >> 3;
  return (xcd < r ? xcd * (q + 1) : r * (q + 1) + (xcd - r) * q) + pos;
}

// ---------------- NCHW fp32 -> padded NHWC bf16 ----------------
__global__ __launch_bounds__(256)
void transpose_feat(const float* __restrict__ src, u16* __restrict__ dst) {
  __shared__ float tile[128][17];
  const int bh = blockIdx.y;            // 0..143
  const int b = bh / 18, h = bh % 18;
  const int wt = blockIdx.x % 5, ct = blockIdx.x / 5;
  const int w0 = wt * 16, c0 = ct * 128;
  const int tid = threadIdx.x;
#pragma unroll
  for (int it = 0; it < 8; ++it) {
    int idx = it * 256 + tid;
    int c = idx >> 4, w = idx & 15;
    tile[c][w] = src[((size_t)(b * 1024 + c0 + c) * 18 + h) * 80 + w0 + w];
  }
  __syncthreads();
  const int px = tid >> 4, cq = tid & 15;
  union { uint4 u; u16 s[8]; } pk;
#pragma unroll
  for (int j = 0; j < 8; ++j) pk.s[j] = f2bf(tile[cq * 8 + j][px]);
  *(uint4*)(dst + ((size_t)(b * 20 + h + 1) * 82 + (w0 + px + 1)) * 1024 + c0 + cq * 8) = pk.u;
}

// ---------------- merged weight repack: 7 tensors in one dispatch ----------------
struct RepackArgs {
  const float* src[7];
  u16* dst[7];
  int O[7];
  int start[7];
  int nseg;
};

__global__ __launch_bounds__(256)
void repack_all(RepackArgs ra) {
  int blk = blockIdx.x;
  int seg = 0;
#pragma unroll
  for (int i = 1; i < 7; ++i)
    if (i < ra.nseg && blk >= ra.start[i]) seg = i;
  const float* src = ra.src[seg];
  u16* dst = ra.dst[seg];
  const int O = ra.O[seg];
  int idx = (blk - ra.start[seg]) * 256 + threadIdx.x;
  if (idx >= O * 128) return;
  int o = idx >> 7, c8 = idx & 127;
  const float* s = src + (size_t)o * 9216 + (size_t)c8 * 72;
  float v[72];
#pragma unroll
  for (int i = 0; i < 18; ++i) {
    float4 f = *(const float4*)(s + i * 4);
    v[i * 4 + 0] = f.x; v[i * 4 + 1] = f.y; v[i * 4 + 2] = f.z; v[i * 4 + 3] = f.w;
  }
#pragma unroll
  for (int t = 0; t < 9; ++t) {
    union { uint4 u; u16 h[8]; } pk;
#pragma unroll
    for (int j = 0; j < 8; ++j) pk.h[j] = f2bf(v[j * 9 + t]);
    *(uint4*)(dst + ((size_t)t * O + o) * 1024 + c8 * 8) = pk.u;
  }
}

// ---------------- deformable bilinear sampling (device body) ----------------
__device__ __forceinline__
void sample_body(int k, int lp, int pix0, int Npc,
                 const u16* __restrict__ featP, const float* __restrict__ offp,
                 u16* __restrict__ spl, int tid) {
  const int p = pix0 + lp;
  const int c8 = tid & 15;
  int b = p / HW, hw = p - b * HW;
  int h = hw / 80, w = hw - h * 80;
  float dy = offp[p * 27 + k];
  float dx = offp[p * 27 + 9 + k];
  float ml = offp[p * 27 + 18 + k];
  float m = 1.f / (1.f + expf(-ml));
  float py = (float)(h - 1 + k / 3) + dy;
  float px = (float)(w - 1 + (k % 3)) + dx;
  float y0f = floorf(py), x0f = floorf(px);
  float wy1 = py - y0f, wx1 = px - x0f;
  float wy0 = 1.f - wy1, wx0 = 1.f - wx1;
  int y0 = (int)y0f, x0 = (int)x0f;
  int ya = min(max(y0, -1), 18),  yb = min(max(y0 + 1, -1), 18);
  int xa = min(max(x0, -1), 80),  xb = min(max(x0 + 1, -1), 80);
  const u16* base = featP + (size_t)b * PBAT;
  const u16* r00 = base + ((size_t)(ya + 1) * 82 + (xa + 1)) * 1024;
  const u16* r01 = base + ((size_t)(ya + 1) * 82 + (xb + 1)) * 1024;
  const u16* r10 = base + ((size_t)(yb + 1) * 82 + (xa + 1)) * 1024;
  const u16* r11 = base + ((size_t)(yb + 1) * 82 + (xb + 1)) * 1024;
  float w00 = wy0 * wx0 * m, w01 = wy0 * wx1 * m;
  float w10 = wy1 * wx0 * m, w11 = wy1 * wx1 * m;
  u16* dst = spl + ((size_t)k * Npc + lp) * 1024;
  for (int c = c8 * 8; c < 1024; c += 128) {
    union { uint4 u; u16 h[8]; } a, bq, cq2, d, o;
    a.u   = *(const uint4*)(r00 + c);
    bq.u  = *(const uint4*)(r01 + c);
    cq2.u = *(const uint4*)(r10 + c);
    d.u   = *(const uint4*)(r11 + c);
#pragma unroll
    for (int j = 0; j < 8; ++j) {
      float v = w00 * bf2f(a.h[j]) + w01 * bf2f(bq.h[j]) +
                w10 * bf2f(cq2.h[j]) + w11 * bf2f(d.h[j]);
      o.h[j] = f2bf(v);
    }
    *(uint4*)(dst + c) = o.u;
  }
}

__global__ __launch_bounds__(256)
void sample_standalone(const u16* __restrict__ featP, const float* __restrict__ offp,
                       u16* __restrict__ spl, int pix0, int Npc) {
  sample_body(blockIdx.y, blockIdx.x * 16 + (threadIdx.x >> 4), pix0, Npc,
              featP, offp, spl, threadIdx.x);
}

// FLAGS: 1 = planes-B, 2 = store fp32 flat [p][Co], 4 = BN, 8 = ReLU
struct Job {
  const u16* W; const u16* B;
  const float* bias; const float* bng; const float* bnb;
  void* out; int Co; int pix0; int Npc;
};

// One shared 16 KB LDS block per kernel, passed in (avoids the per-template-
// instantiation duplication that made the original kernels carry 32 KB).
constexpr int LDSU16 = 8192;   // As = lds[0..4096), Bs = lds[4096..8192)

// ---------------- 128x128 2-barrier drain MFMA body (round-0 proven) ----------------
template<int FLAGS>
__device__ __forceinline__ void gemm_body(const Job J, u16* lds, int px, int oy) {
  constexpr bool PLANES  = (FLAGS & 1) != 0;
  constexpr bool F32OUT  = (FLAGS & 2) != 0;
  constexpr bool HASBN   = (FLAGS & 4) != 0;
  constexpr bool HASRELU = (FLAGS & 8) != 0;

  u16* As = lds;
  u16* Bs = lds + 4096;
  const int tid = threadIdx.x;
  const int wv = tid >> 6, lane = tid & 63;
  const int o0 = oy * 128;
  const int p0 = J.pix0 + px * 128;

  const int lr = lane >> 2;
  const int qs = (lane & 3) ^ ((lane >> 3) & 3);
  int aoff[2], boff[2];
#pragma unroll
  for (int s = 0; s < 2; ++s) {
    int r = (wv * 2 + s) * 16 + lr;
    int o = min(o0 + r, J.Co - 1);
    aoff[s] = o * 1024 + qs * 8;
    int p = p0 + r;
    if (PLANES) {
      boff[s] = (p - J.pix0) * 1024 + qs * 8;
    } else {
      int b = p / HW, hw = p - b * HW;
      int h = hw / 80, w = hw - h * 80;
      boff[s] = ((b * 20 + h) * 82 + w) * 1024 + qs * 8;
    }
  }
  u16* aDst = As + (wv * 2) * 512;
  u16* bDst = Bs + (wv * 2) * 512;

  const int wm = wv >> 1, wn = wv & 1;
  const int frm = lane & 15;
  const int kq = lane >> 4;
  const int sel = (kq ^ ((lane >> 1) & 3)) * 16;

  f32x4 acc[4][4];
#pragma unroll
  for (int i = 0; i < 4; ++i)
#pragma unroll
    for (int j = 0; j < 4; ++j) acc[i][j] = (f32x4)0.f;

  for (int t = 0; t < 9; ++t) {
    const u16* Wt = J.W + (size_t)t * J.Co * 1024;
    const u16* Bt = J.B + (PLANES ? (size_t)t * (size_t)J.Npc * 1024
                                  : (size_t)(((t / 3) * 82 + (t % 3)) * 1024));
    for (int cc = 0; cc < 1024; cc += 32) {
      __syncthreads();
#pragma unroll
      for (int s = 0; s < 2; ++s) {
        __builtin_amdgcn_global_load_lds(GAS(Wt + aoff[s] + cc), LAS(aDst + s * 512), 16, 0, 0);
        __builtin_amdgcn_global_load_lds(GAS(Bt + boff[s] + cc), LAS(bDst + s * 512), 16, 0, 0);
      }
      __syncthreads();
      uint4 af[4], bf4[4];
#pragma unroll
      for (int i = 0; i < 4; ++i) {
        af[i]  = *(const uint4*)((const char*)As + (wm * 64 + i * 16 + frm) * 64 + sel);
        bf4[i] = *(const uint4*)((const char*)Bs + (wn * 64 + i * 16 + frm) * 64 + sel);
      }
#pragma unroll
      for (int i = 0; i < 4; ++i) {
        short8 a = __builtin_bit_cast(short8, af[i]);
#pragma unroll
        for (int j = 0; j < 4; ++j) {
          short8 b = __builtin_bit_cast(short8, bf4[j]);
          acc[i][j] = __builtin_amdgcn_mfma_f32_16x16x32_bf16(a, b, acc[i][j], 0, 0, 0);
        }
      }
    }
  }

  size_t obase[4];
#pragma unroll
  for (int j = 0; j < 4; ++j) {
    int pn = p0 + wn * 64 + j * 16 + frm;
    if (F32OUT) {
      obase[j] = (size_t)pn * J.Co;
    } else {
      int b = pn / HW, hw = pn - b * HW;
      int h = hw / 80, w = hw - h * 80;
      obase[j] = ((size_t)(b * 20 + h + 1) * 82 + (w + 1)) * 1024;
    }
  }
#pragma unroll
  for (int i = 0; i < 4; ++i) {
    int o = o0 + wm * 64 + i * 16 + kq * 4;
    float bi[4], sc[4], sh[4];
#pragma unroll
    for (int r = 0; r < 4; ++r) {
      int oc = min(o + r, J.Co - 1);
      bi[r] = J.bias[oc];
      if (HASBN) { sc[r] = J.bng[oc] * rsqrtf(1.f + 1e-5f); sh[r] = J.bnb[oc]; }
    }
#pragma unroll
    for (int j = 0; j < 4; ++j) {
      float v[4];
#pragma unroll
      for (int r = 0; r < 4; ++r) {
        float x = acc[i][j][r] + bi[r];
        if (HASBN) x = x * sc[r] + sh[r];
        if (HASRELU) x = fmaxf(x, 0.f);
        v[r] = x;
      }
      if (F32OUT) {
        float* op = (float*)J.out;
#pragma unroll
        for (int r = 0; r < 4; ++r)
          if (o + r < J.Co) op[obase[j] + o + r] = v[r];
      } else {
        u16* op = (u16*)J.out;
        ushort4 pk;
        pk.x = f2bf(v[0]); pk.y = f2bf(v[1]); pk.z = f2bf(v[2]); pk.w = f2bf(v[3]);
        *(ushort4*)(op + obase[j] + o) = pk;
      }
    }
  }
}

template<int F0, int F1>
__global__ __launch_bounds__(256)
void gemm_dual(Job j0, Job j1, int ysplit) {
  __shared__ __align__(16) u16 lds[LDSU16];
  // px-major XCD clustering: virt = px*NY + y
  int id = blockIdx.y * gridDim.x + blockIdx.x;
  int virt = xcd_virt(id, gridDim.x * gridDim.y);
  int NY = gridDim.y;
  int px = virt / NY, y = virt % NY;
  if (y < ysplit) gemm_body<F0>(j0, lds, px, y);
  else            gemm_body<F1>(j1, lds, px, y - ysplit);
}

// GEMM job co-scheduled with sampler blocks (16 px each). grid.x = n0 + 9*(nps/16).
template<int F0>
__global__ __launch_bounds__(256)
void gemm_sample(Job j, const u16* __restrict__ featP, const float* __restrict__ offp,
                 u16* __restrict__ spl, int n0, int pix0s, int nps) {
  __shared__ __align__(16) u16 lds[LDSU16];
  int gx = blockIdx.x;
  if (gx < n0) {
    int virt = xcd_virt(gx, n0);         // n0 = 720: px-major over (90 px, 8 oy)
    gemm_body<F0>(j, lds, virt >> 3, virt & 7);
  } else {
    int sidx = gx - n0;
    int per = nps >> 4;
    int k = sidx / per, bs = sidx % per;
    sample_body(k, bs * 16 + ((int)threadIdx.x >> 4), pix0s, nps,
                featP, offp, spl, (int)threadIdx.x);
  }
}

// dcn chunk kernel: [n0: dcn gemm blocks][n1: cls3 head blocks][rest: sampler chunk t+1]
template<int F0, int F1>
__global__ __launch_bounds__(256)
void dcn_chunk(Job j0, Job j1, int n0, int nt0, int n1,
               const u16* __restrict__ featP, const float* __restrict__ offp,
               u16* __restrict__ splNext, int pix0n, int npn) {
  __shared__ __align__(16) u16 lds[LDSU16];
  int x = blockIdx.x;
  if (x < n0) {
    int virt = xcd_virt(x, n0);          // n0 = nt0*8: px-major (px = v/8, oy = v%8)
    gemm_body<F0>(j0, lds, virt >> 3, virt & 7);
    return;
  }
  x -= n0;
  if (x < n1) { gemm_body<F1>(j1, lds, x % 90, x / 90); return; }
  x -= n1;
  int per = npn >> 4;                 // sampler blocks per tap (16 px each)
  int k = x / per, bs = x % per;
  sample_body(k, bs * 16 + ((int)threadIdx.x >> 4), pix0n, npn,
              featP, offp, splNext, (int)threadIdx.x);
}

} // namespace

extern "C" void kernel_launch(void* const* d_in, const int* in_sizes, int n_in,
                              void* d_out, int out_size, void* d_ws, size_t ws_size,
                              hipStream_t stream) {
  const float* feat   = (const float*)d_in[0];
  const float* cls_w1 = (const float*)d_in[1];
  const float* cls_b1 = (const float*)d_in[2];
  const float* cls_w2 = (const float*)d_in[3];
  const float* cls_b2 = (const float*)d_in[4];
  const float* cls_w3 = (const float*)d_in[5];
  const float* cls_b3 = (const float*)d_in[6];
  const float* off_w  = (const float*)d_in[7];
  const float* off_b  = (const float*)d_in[8];
  const float* dcn_w  = (const float*)d_in[9];
  const float* dcn_b  = (const float*)d_in[10];
  const float* bn1_g  = (const float*)d_in[11];
  const float* bn1_b  = (const float*)d_in[12];
  const float* reg_w2 = (const float*)d_in[13];
  const float* reg_b2 = (const float*)d_in[14];
  const float* bn2_g  = (const float*)d_in[15];
  const float* bn2_b  = (const float*)d_in[16];
  const float* reg_w3 = (const float*)d_in[17];
  const float* reg_b3 = (const float*)d_in[18];
  float* outp = (float*)d_out;

  const size_t ACTB = 26869760;                // 8*20*82*1024*2 bytes
  char* wsb = (char*)d_ws;
  u16* featP = (u16*)(wsb);
  u16* bufA  = (u16*)(wsb + ACTB);
  u16* bufB  = (u16*)(wsb + 2 * ACTB);
  u16* wts   = (u16*)(wsb + 3 * ACTB);
  float* offp = (float*)(wsb + 3 * ACTB + 85432320);
  u16* spl   = (u16*)(wsb + 3 * ACTB + 85432320 + 1244160);
  const size_t BASE = 3 * ACTB + 85432320 + 1244160;   // 167,285,760
  const size_t SPLB = (size_t)9 * 11520 * 1024 * 2;    // 212,336,640

  u16* offT = wts;
  u16* w1T  = wts + 248832;
  u16* w2T  = wts + 9686016;
  u16* w3T  = wts + 19123200;
  u16* dcnT = wts + 20007936;
  u16* r2T  = wts + 29445120;
  u16* r3T  = wts + 38882304;

  dim3 blk(256);

  hipMemsetAsync(featP, 0, 3 * ACTB, stream);
  transpose_feat<<<dim3(40, 144), blk, 0, stream>>>(feat, featP);

  {
    RepackArgs ra;
    const float* s[7] = {off_w, cls_w1, cls_w2, cls_w3, dcn_w, reg_w2, reg_w3};
    u16* d[7] = {offT, w1T, w2T, w3T, dcnT, r2T, r3T};
    int  O[7] = {27, 1024, 1024, 96, 1024, 1024, 416};
    int acc = 0;
    for (int i = 0; i < 7; ++i) {
      ra.src[i] = s[i]; ra.dst[i] = d[i]; ra.O[i] = O[i]; ra.start[i] = acc;
      acc += (O[i] * 128 + 255) / 256;
    }
    ra.nseg = 7;
    repack_all<<<dim3(acc), blk, 0, stream>>>(ra);
  }

  Job jOff  = {offT, featP, off_b, nullptr, nullptr, offp, 27, 0, 0};
  Job jCls1 = {w1T, featP, cls_b1, nullptr, nullptr, bufA, 1024, 0, 0};
  Job jCls2 = {w2T, bufA, cls_b2, nullptr, nullptr, bufB, 1024, 0, 0};
  Job jCls3 = {w3T, bufB, cls_b3, nullptr, nullptr, outp, 96, 0, 0};
  Job jReg2 = {r2T, bufA, reg_b2, bn2_g, bn2_b, bufB, 1024, 0, 0};
  Job jReg3 = {r3T, bufB, reg_b3, nullptr, nullptr, outp + 1105920, 416, 0, 0};

  size_t avail = ws_size > BASE ? ws_size - BASE : 0;

  // pick chunk size (in 128-px tiles) for ping-pong sampling; 0 = doesn't fit
  int tch = 0;
  {
    const int cand[5] = {30, 18, 15, 10, 9};
    for (int i = 0; i < 5; ++i)
      if ((size_t)2 * cand[i] * 2359296 <= avail) { tch = cand[i]; break; }
  }

  // D2: cls1 (relu->bf16, y<8) + offset conv (f32 flat, y==8; shares featP B)
  gemm_dual<8, 2><<<dim3(90, 9), blk, 0, stream>>>(jCls1, jOff, 8);

  if (avail >= SPLB) {
    // ---- tier 1: full spl fits ----
    gemm_sample<8><<<dim3(720 + 6480), blk, 0, stream>>>(jCls2, featP, offp, spl, 720, 0, 11520);
    Job jDcn = {dcnT, spl, dcn_b, bn1_g, bn1_b, bufA, 1024, 0, 11520};
    gemm_dual<1 | 4 | 8, 2><<<dim3(90, 9), blk, 0, stream>>>(jDcn, jCls3, 8);
    gemm_dual<4 | 8, 4 | 8><<<dim3(90, 8), blk, 0, stream>>>(jReg2, jReg2, 8);
    gemm_dual<2, 2><<<dim3(90, 4), blk, 0, stream>>>(jReg3, jReg3, 4);
  } else if (tch > 0) {
    // ---- tier 2: chunked ping-pong sampling ----
    const int C = 90 / tch;
    const int np = tch * 128;
    u16* splA = spl;
    u16* splB = spl + (size_t)tch * 1179648;   // elements

    // D3: cls2 (720) + sample chunk0 -> splA
    gemm_sample<8><<<dim3(720 + 9 * (np / 16)), blk, 0, stream>>>(
        jCls2, featP, offp, splA, 720, 0, np);
    // chunk loop: dcn chunk i (+cls3 in chunk0) + sample chunk i+1
    for (int i = 0; i < C; ++i) {
      u16* sCur  = (i & 1) ? splB : splA;
      u16* sNext = (i & 1) ? splA : splB;
      Job jDcnC = {dcnT, sCur, dcn_b, bn1_g, bn1_b, bufA, 1024, i * np, np};
      int n0 = tch * 8;
      int n1 = (i == 0) ? 90 : 0;
      bool hasS = (i + 1 < C);
      int ns = hasS ? 9 * (np / 16) : 0;
      dcn_chunk<1 | 4 | 8, 2><<<dim3(n0 + n1 + ns), blk, 0, stream>>>(
          jDcnC, jCls3, n0, tch, n1,
          featP, offp, sNext, (i + 1) * np, hasS ? np : 16);
    }
    gemm_dual<4 | 8, 4 | 8><<<dim3(90, 8), blk, 0, stream>>>(jReg2, jReg2, 8);
    gemm_dual<2, 2><<<dim3(90, 4), blk, 0, stream>>>(jReg3, jReg3, 4);
  } else {
    // ---- tier 3: serial chunked fallback ----
    gemm_dual<8, 8><<<dim3(90, 8), blk, 0, stream>>>(jCls2, jCls2, 8);
    int tiles = (int)(avail / 2359296);
    if (tiles < 1) tiles = 1;
    if (tiles > 90) tiles = 90;
    for (int t0 = 0; t0 < 90; t0 += tiles) {
      int nt = (90 - t0) < tiles ? (90 - t0) : tiles;
      int pix0 = t0 * 128, npp = nt * 128;
      sample_standalone<<<dim3(nt * 8, 9), blk, 0, stream>>>(featP, offp, spl, pix0, npp);
      Job jDcn = {dcnT, spl, dcn_b, bn1_g, bn1_b, bufA, 1024, pix0, npp};
      gemm_dual<1 | 4 | 8, 1 | 4 | 8><<<dim3(nt, 8), blk, 0, stream>>>(jDcn, jDcn, 8);
    }
    gemm_dual<2, 2><<<dim3(90, 1), blk, 0, stream>>>(jCls3, jCls3, 1);
    gemm_dual<4 | 8, 4 | 8><<<dim3(90, 8), blk, 0, stream>>>(jReg2, jReg2, 8);
    gemm_dual<2, 2><<<dim3(90, 4), blk, 0, stream>>>(jReg3, jReg3, 4);
  }
}

// Round 7
// 1979.691 us; speedup vs baseline: 1.3303x; 1.0589x over previous
//
#include <hip/hip_runtime.h>
#include <math.h>

typedef short short8 __attribute__((ext_vector_type(8)));
typedef float f32x4 __attribute__((ext_vector_type(4)));
typedef unsigned short u16;
typedef unsigned int u32;

#define GAS(p) ((__attribute__((address_space(1))) void*)(p))
#define LAS(p) ((__attribute__((address_space(3))) void*)(p))

namespace {

constexpr int HW   = 1440;           // 18*80
constexpr int PBAT = 20 * 82 * 1024; // padded per-batch elems

__device__ __forceinline__ u16 f2bf(float f) {
  u32 u = __float_as_uint(f);
  return (u16)((u + 0x7FFFu + ((u >> 16) & 1u)) >> 16);
}
__device__ __forceinline__ float bf2f(u16 h) {
  return __uint_as_float(((u32)h) << 16);
}

// XCD-aware bijective remap (m204): dispatch id -> virt; each of 8 XCDs
// (id%8 under round-robin) owns a CONTIGUOUS virt range. Caller decodes virt
// PX-MAJOR (px = virt/NY, oy = virt%NY) so an XCD gets a contiguous px range
// with ALL oy: the 9 B-panel sharers (same px, diff oy) are co-XCD => B
// fetched ~once. (R6 verified: FETCH 958->222 MB.)
__device__ __forceinline__ int xcd_virt(int id, int N) {
  int q = N >> 3, r = N & 7;
  int xcd = id & 7, pos = id >> 3;
  return (xcd < r ? xcd * (q + 1) : r * (q + 1) + (xcd - r) * q) + pos;
}

// ---------------- NCHW fp32 -> padded NHWC bf16 ----------------
__global__ __launch_bounds__(256)
void transpose_feat(const float* __restrict__ src, u16* __restrict__ dst) {
  __shared__ float tile[128][17];
  const int bh = blockIdx.y;            // 0..143
  const int b = bh / 18, h = bh % 18;
  const int wt = blockIdx.x % 5, ct = blockIdx.x / 5;
  const int w0 = wt * 16, c0 = ct * 128;
  const int tid = threadIdx.x;
#pragma unroll
  for (int it = 0; it < 8; ++it) {
    int idx = it * 256 + tid;
    int c = idx >> 4, w = idx & 15;
    tile[c][w] = src[((size_t)(b * 1024 + c0 + c) * 18 + h) * 80 + w0 + w];
  }
  __syncthreads();
  const int px = tid >> 4, cq = tid & 15;
  union { uint4 u; u16 s[8]; } pk;
#pragma unroll
  for (int j = 0; j < 8; ++j) pk.s[j] = f2bf(tile[cq * 8 + j][px]);
  *(uint4*)(dst + ((size_t)(b * 20 + h + 1) * 82 + (w0 + px + 1)) * 1024 + c0 + cq * 8) = pk.u;
}

// ---------------- merged weight repack: 7 tensors in one dispatch ----------------
struct RepackArgs {
  const float* src[7];
  u16* dst[7];
  int O[7];
  int start[7];
  int nseg;
};

__global__ __launch_bounds__(256)
void repack_all(RepackArgs ra) {
  int blk = blockIdx.x;
  int seg = 0;
#pragma unroll
  for (int i = 1; i < 7; ++i)
    if (i < ra.nseg && blk >= ra.start[i]) seg = i;
  const float* src = ra.src[seg];
  u16* dst = ra.dst[seg];
  const int O = ra.O[seg];
  int idx = (blk - ra.start[seg]) * 256 + threadIdx.x;
  if (idx >= O * 128) return;
  int o = idx >> 7, c8 = idx & 127;
  const float* s = src + (size_t)o * 9216 + (size_t)c8 * 72;
  float v[72];
#pragma unroll
  for (int i = 0; i < 18; ++i) {
    float4 f = *(const float4*)(s + i * 4);
    v[i * 4 + 0] = f.x; v[i * 4 + 1] = f.y; v[i * 4 + 2] = f.z; v[i * 4 + 3] = f.w;
  }
#pragma unroll
  for (int t = 0; t < 9; ++t) {
    union { uint4 u; u16 h[8]; } pk;
#pragma unroll
    for (int j = 0; j < 8; ++j) pk.h[j] = f2bf(v[j * 9 + t]);
    *(uint4*)(dst + ((size_t)t * O + o) * 1024 + c8 * 8) = pk.u;
  }
}

// ---------------- deformable bilinear sampling (device body) ----------------
__device__ __forceinline__
void sample_body(int k, int lp, int pix0, int Npc,
                 const u16* __restrict__ featP, const float* __restrict__ offp,
                 u16* __restrict__ spl, int tid) {
  const int p = pix0 + lp;
  const int c8 = tid & 15;
  int b = p / HW, hw = p - b * HW;
  int h = hw / 80, w = hw - h * 80;
  float dy = offp[p * 27 + k];
  float dx = offp[p * 27 + 9 + k];
  float ml = offp[p * 27 + 18 + k];
  float m = 1.f / (1.f + expf(-ml));
  float py = (float)(h - 1 + k / 3) + dy;
  float px = (float)(w - 1 + (k % 3)) + dx;
  float y0f = floorf(py), x0f = floorf(px);
  float wy1 = py - y0f, wx1 = px - x0f;
  float wy0 = 1.f - wy1, wx0 = 1.f - wx1;
  int y0 = (int)y0f, x0 = (int)x0f;
  int ya = min(max(y0, -1), 18),  yb = min(max(y0 + 1, -1), 18);
  int xa = min(max(x0, -1), 80),  xb = min(max(x0 + 1, -1), 80);
  const u16* base = featP + (size_t)b * PBAT;
  const u16* r00 = base + ((size_t)(ya + 1) * 82 + (xa + 1)) * 1024;
  const u16* r01 = base + ((size_t)(ya + 1) * 82 + (xb + 1)) * 1024;
  const u16* r10 = base + ((size_t)(yb + 1) * 82 + (xa + 1)) * 1024;
  const u16* r11 = base + ((size_t)(yb + 1) * 82 + (xb + 1)) * 1024;
  float w00 = wy0 * wx0 * m, w01 = wy0 * wx1 * m;
  float w10 = wy1 * wx0 * m, w11 = wy1 * wx1 * m;
  u16* dst = spl + ((size_t)k * Npc + lp) * 1024;
  for (int c = c8 * 8; c < 1024; c += 128) {
    union { uint4 u; u16 h[8]; } a, bq, cq2, d, o;
    a.u   = *(const uint4*)(r00 + c);
    bq.u  = *(const uint4*)(r01 + c);
    cq2.u = *(const uint4*)(r10 + c);
    d.u   = *(const uint4*)(r11 + c);
#pragma unroll
    for (int j = 0; j < 8; ++j) {
      float v = w00 * bf2f(a.h[j]) + w01 * bf2f(bq.h[j]) +
                w10 * bf2f(cq2.h[j]) + w11 * bf2f(d.h[j]);
      o.h[j] = f2bf(v);
    }
    *(uint4*)(dst + c) = o.u;
  }
}

__global__ __launch_bounds__(256)
void sample_standalone(const u16* __restrict__ featP, const float* __restrict__ offp,
                       u16* __restrict__ spl, int pix0, int Npc) {
  sample_body(blockIdx.y, blockIdx.x * 16 + (threadIdx.x >> 4), pix0, Npc,
              featP, offp, spl, threadIdx.x);
}

// FLAGS: 1 = planes-B, 2 = store fp32 flat [p][Co], 4 = BN, 8 = ReLU
struct Job {
  const u16* W; const u16* B;
  const float* bias; const float* bng; const float* bnb;
  void* out; int Co; int pix0; int Npc;
};

// One shared 32 KB LDS block per kernel, passed in (avoids per-template-
// instantiation duplication).
constexpr int LDSU16 = 16384;  // As = lds[0..8192), Bs = lds[8192..16384)

// ---------------- 128x128 drain MFMA body, BK=64 ----------------
// Per K-step: stage two 32-ch sub-slabs (8 gload_lds/thread), ONE vmcnt(0)
// drain + 2 barriers, then 32 MFMA/wave. Halves the number of drains vs BK=32
// (144 vs 288) at constant occupancy (32 KB LDS -> still 3+ blocks/CU).
template<int FLAGS>
__device__ __forceinline__ void gemm_body(const Job J, u16* lds, int px, int oy) {
  constexpr bool PLANES  = (FLAGS & 1) != 0;
  constexpr bool F32OUT  = (FLAGS & 2) != 0;
  constexpr bool HASBN   = (FLAGS & 4) != 0;
  constexpr bool HASRELU = (FLAGS & 8) != 0;

  u16* As = lds;
  u16* Bs = lds + 8192;
  const int tid = threadIdx.x;
  const int wv = tid >> 6, lane = tid & 63;
  const int o0 = oy * 128;
  const int p0 = J.pix0 + px * 128;

  const int lr = lane >> 2;
  const int qs = (lane & 3) ^ ((lane >> 3) & 3);
  int aoff[2], boff[2];
#pragma unroll
  for (int s = 0; s < 2; ++s) {
    int r = (wv * 2 + s) * 16 + lr;
    int o = min(o0 + r, J.Co - 1);
    aoff[s] = o * 1024 + qs * 8;
    int p = p0 + r;
    if (PLANES) {
      boff[s] = (p - J.pix0) * 1024 + qs * 8;
    } else {
      int b = p / HW, hw = p - b * HW;
      int h = hw / 80, w = hw - h * 80;
      boff[s] = ((b * 20 + h) * 82 + w) * 1024 + qs * 8;
    }
  }
  u16* aDst = As + (wv * 2) * 512;   // within sub-slab 0; sub-slab 1 at +4096
  u16* bDst = Bs + (wv * 2) * 512;

  const int wm = wv >> 1, wn = wv & 1;
  const int frm = lane & 15;
  const int kq = lane >> 4;
  const int sel = (kq ^ ((lane >> 1) & 3)) * 16;

  f32x4 acc[4][4];
#pragma unroll
  for (int i = 0; i < 4; ++i)
#pragma unroll
    for (int j = 0; j < 4; ++j) acc[i][j] = (f32x4)0.f;

  for (int t = 0; t < 9; ++t) {
    const u16* Wt = J.W + (size_t)t * J.Co * 1024;
    const u16* Bt = J.B + (PLANES ? (size_t)t * (size_t)J.Npc * 1024
                                  : (size_t)(((t / 3) * 82 + (t % 3)) * 1024));
    for (int cc = 0; cc < 1024; cc += 64) {
      __syncthreads();
#pragma unroll
      for (int s2 = 0; s2 < 2; ++s2) {
#pragma unroll
        for (int s = 0; s < 2; ++s) {
          __builtin_amdgcn_global_load_lds(GAS(Wt + aoff[s] + cc + s2 * 32),
                                           LAS(aDst + s2 * 4096 + s * 512), 16, 0, 0);
          __builtin_amdgcn_global_load_lds(GAS(Bt + boff[s] + cc + s2 * 32),
                                           LAS(bDst + s2 * 4096 + s * 512), 16, 0, 0);
        }
      }
      __syncthreads();   // compiler emits s_waitcnt vmcnt(0) lgkmcnt(0) before barrier
#pragma unroll
      for (int s2 = 0; s2 < 2; ++s2) {
        const char* Ab = (const char*)As + s2 * 8192;
        const char* Bb = (const char*)Bs + s2 * 8192;
        uint4 af[4], bf4[4];
#pragma unroll
        for (int i = 0; i < 4; ++i) {
          af[i]  = *(const uint4*)(Ab + (wm * 64 + i * 16 + frm) * 64 + sel);
          bf4[i] = *(const uint4*)(Bb + (wn * 64 + i * 16 + frm) * 64 + sel);
        }
#pragma unroll
        for (int i = 0; i < 4; ++i) {
          short8 a = __builtin_bit_cast(short8, af[i]);
#pragma unroll
          for (int j = 0; j < 4; ++j) {
            short8 b = __builtin_bit_cast(short8, bf4[j]);
            acc[i][j] = __builtin_amdgcn_mfma_f32_16x16x32_bf16(a, b, acc[i][j], 0, 0, 0);
          }
        }
      }
    }
  }

  size_t obase[4];
#pragma unroll
  for (int j = 0; j < 4; ++j) {
    int pn = p0 + wn * 64 + j * 16 + frm;
    if (F32OUT) {
      obase[j] = (size_t)pn * J.Co;
    } else {
      int b = pn / HW, hw = pn - b * HW;
      int h = hw / 80, w = hw - h * 80;
      obase[j] = ((size_t)(b * 20 + h + 1) * 82 + (w + 1)) * 1024;
    }
  }
#pragma unroll
  for (int i = 0; i < 4; ++i) {
    int o = o0 + wm * 64 + i * 16 + kq * 4;
    float bi[4], sc[4], sh[4];
#pragma unroll
    for (int r = 0; r < 4; ++r) {
      int oc = min(o + r, J.Co - 1);
      bi[r] = J.bias[oc];
      if (HASBN) { sc[r] = J.bng[oc] * rsqrtf(1.f + 1e-5f); sh[r] = J.bnb[oc]; }
    }
#pragma unroll
    for (int j = 0; j < 4; ++j) {
      float v[4];
#pragma unroll
      for (int r = 0; r < 4; ++r) {
        float x = acc[i][j][r] + bi[r];
        if (HASBN) x = x * sc[r] + sh[r];
        if (HASRELU) x = fmaxf(x, 0.f);
        v[r] = x;
      }
      if (F32OUT) {
        float* op = (float*)J.out;
#pragma unroll
        for (int r = 0; r < 4; ++r)
          if (o + r < J.Co) op[obase[j] + o + r] = v[r];
      } else {
        u16* op = (u16*)J.out;
        ushort4 pk;
        pk.x = f2bf(v[0]); pk.y = f2bf(v[1]); pk.z = f2bf(v[2]); pk.w = f2bf(v[3]);
        *(ushort4*)(op + obase[j] + o) = pk;
      }
    }
  }
}

template<int F0, int F1>
__global__ __launch_bounds__(256)
void gemm_dual(Job j0, Job j1, int ysplit) {
  __shared__ __align__(16) u16 lds[LDSU16];
  // px-major XCD clustering: virt = px*NY + y
  int id = blockIdx.y * gridDim.x + blockIdx.x;
  int virt = xcd_virt(id, gridDim.x * gridDim.y);
  int NY = gridDim.y;
  int px = virt / NY, y = virt % NY;
  if (y < ysplit) gemm_body<F0>(j0, lds, px, y);
  else            gemm_body<F1>(j1, lds, px, y - ysplit);
}

// GEMM job co-scheduled with sampler blocks (16 px each). grid.x = n0 + 9*(nps/16).
template<int F0>
__global__ __launch_bounds__(256)
void gemm_sample(Job j, const u16* __restrict__ featP, const float* __restrict__ offp,
                 u16* __restrict__ spl, int n0, int pix0s, int nps) {
  __shared__ __align__(16) u16 lds[LDSU16];
  int gx = blockIdx.x;
  if (gx < n0) {
    int virt = xcd_virt(gx, n0);         // n0 = 720: px-major over (90 px, 8 oy)
    gemm_body<F0>(j, lds, virt >> 3, virt & 7);
  } else {
    int sidx = gx - n0;
    int per = nps >> 4;
    int k = sidx / per, bs = sidx % per;
    sample_body(k, bs * 16 + ((int)threadIdx.x >> 4), pix0s, nps,
                featP, offp, spl, (int)threadIdx.x);
  }
}

// dcn chunk kernel: [n0: dcn gemm blocks][n1: cls3 head blocks][rest: sampler chunk t+1]
template<int F0, int F1>
__global__ __launch_bounds__(256)
void dcn_chunk(Job j0, Job j1, int n0, int nt0, int n1,
               const u16* __restrict__ featP, const float* __restrict__ offp,
               u16* __restrict__ splNext, int pix0n, int npn) {
  __shared__ __align__(16) u16 lds[LDSU16];
  int x = blockIdx.x;
  if (x < n0) {
    int virt = xcd_virt(x, n0);          // n0 = nt0*8: px-major (px = v/8, oy = v%8)
    gemm_body<F0>(j0, lds, virt >> 3, virt & 7);
    return;
  }
  x -= n0;
  if (x < n1) { gemm_body<F1>(j1, lds, x % 90, x / 90); return; }
  x -= n1;
  int per = npn >> 4;                 // sampler blocks per tap (16 px each)
  int k = x / per, bs = x % per;
  sample_body(k, bs * 16 + ((int)threadIdx.x >> 4), pix0n, npn,
              featP, offp, splNext, (int)threadIdx.x);
}

} // namespace

extern "C" void kernel_launch(void* const* d_in, const int* in_sizes, int n_in,
                              void* d_out, int out_size, void* d_ws, size_t ws_size,
                              hipStream_t stream) {
  const float* feat   = (const float*)d_in[0];
  const float* cls_w1 = (const float*)d_in[1];
  const float* cls_b1 = (const float*)d_in[2];
  const float* cls_w2 = (const float*)d_in[3];
  const float* cls_b2 = (const float*)d_in[4];
  const float* cls_w3 = (const float*)d_in[5];
  const float* cls_b3 = (const float*)d_in[6];
  const float* off_w  = (const float*)d_in[7];
  const float* off_b  = (const float*)d_in[8];
  const float* dcn_w  = (const float*)d_in[9];
  const float* dcn_b  = (const float*)d_in[10];
  const float* bn1_g  = (const float*)d_in[11];
  const float* bn1_b  = (const float*)d_in[12];
  const float* reg_w2 = (const float*)d_in[13];
  const float* reg_b2 = (const float*)d_in[14];
  const float* bn2_g  = (const float*)d_in[15];
  const float* bn2_b  = (const float*)d_in[16];
  const float* reg_w3 = (const float*)d_in[17];
  const float* reg_b3 = (const float*)d_in[18];
  float* outp = (float*)d_out;

  const size_t ACTB = 26869760;                // 8*20*82*1024*2 bytes
  char* wsb = (char*)d_ws;
  u16* featP = (u16*)(wsb);
  u16* bufA  = (u16*)(wsb + ACTB);
  u16* bufB  = (u16*)(wsb + 2 * ACTB);
  u16* wts   = (u16*)(wsb + 3 * ACTB);
  float* offp = (float*)(wsb + 3 * ACTB + 85432320);
  u16* spl   = (u16*)(wsb + 3 * ACTB + 85432320 + 1244160);
  const size_t BASE = 3 * ACTB + 85432320 + 1244160;   // 167,285,760
  const size_t SPLB = (size_t)9 * 11520 * 1024 * 2;    // 212,336,640

  u16* offT = wts;
  u16* w1T  = wts + 248832;
  u16* w2T  = wts + 9686016;
  u16* w3T  = wts + 19123200;
  u16* dcnT = wts + 20007936;
  u16* r2T  = wts + 29445120;
  u16* r3T  = wts + 38882304;

  dim3 blk(256);

  hipMemsetAsync(featP, 0, 3 * ACTB, stream);
  transpose_feat<<<dim3(40, 144), blk, 0, stream>>>(feat, featP);

  {
    RepackArgs ra;
    const float* s[7] = {off_w, cls_w1, cls_w2, cls_w3, dcn_w, reg_w2, reg_w3};
    u16* d[7] = {offT, w1T, w2T, w3T, dcnT, r2T, r3T};
    int  O[7] = {27, 1024, 1024, 96, 1024, 1024, 416};
    int acc = 0;
    for (int i = 0; i < 7; ++i) {
      ra.src[i] = s[i]; ra.dst[i] = d[i]; ra.O[i] = O[i]; ra.start[i] = acc;
      acc += (O[i] * 128 + 255) / 256;
    }
    ra.nseg = 7;
    repack_all<<<dim3(acc), blk, 0, stream>>>(ra);
  }

  Job jOff  = {offT, featP, off_b, nullptr, nullptr, offp, 27, 0, 0};
  Job jCls1 = {w1T, featP, cls_b1, nullptr, nullptr, bufA, 1024, 0, 0};
  Job jCls2 = {w2T, bufA, cls_b2, nullptr, nullptr, bufB, 1024, 0, 0};
  Job jCls3 = {w3T, bufB, cls_b3, nullptr, nullptr, outp, 96, 0, 0};
  Job jReg2 = {r2T, bufA, reg_b2, bn2_g, bn2_b, bufB, 1024, 0, 0};
  Job jReg3 = {r3T, bufB, reg_b3, nullptr, nullptr, outp + 1105920, 416, 0, 0};

  size_t avail = ws_size > BASE ? ws_size - BASE : 0;

  // pick chunk size (in 128-px tiles) for ping-pong sampling; 0 = doesn't fit
  int tch = 0;
  {
    const int cand[5] = {30, 18, 15, 10, 9};
    for (int i = 0; i < 5; ++i)
      if ((size_t)2 * cand[i] * 2359296 <= avail) { tch = cand[i]; break; }
  }

  // D2: cls1 (relu->bf16, y<8) + offset conv (f32 flat, y==8; shares featP B)
  gemm_dual<8, 2><<<dim3(90, 9), blk, 0, stream>>>(jCls1, jOff, 8);

  if (avail >= SPLB) {
    // ---- tier 1: full spl fits ----
    gemm_sample<8><<<dim3(720 + 6480), blk, 0, stream>>>(jCls2, featP, offp, spl, 720, 0, 11520);
    Job jDcn = {dcnT, spl, dcn_b, bn1_g, bn1_b, bufA, 1024, 0, 11520};
    gemm_dual<1 | 4 | 8, 2><<<dim3(90, 9), blk, 0, stream>>>(jDcn, jCls3, 8);
    gemm_dual<4 | 8, 4 | 8><<<dim3(90, 8), blk, 0, stream>>>(jReg2, jReg2, 8);
    gemm_dual<2, 2><<<dim3(90, 4), blk, 0, stream>>>(jReg3, jReg3, 4);
  } else if (tch > 0) {
    // ---- tier 2: chunked ping-pong sampling ----
    const int C = 90 / tch;
    const int np = tch * 128;
    u16* splA = spl;
    u16* splB = spl + (size_t)tch * 1179648;   // elements

    // D3: cls2 (720) + sample chunk0 -> splA
    gemm_sample<8><<<dim3(720 + 9 * (np / 16)), blk, 0, stream>>>(
        jCls2, featP, offp, splA, 720, 0, np);
    // chunk loop: dcn chunk i (+cls3 in chunk0) + sample chunk i+1
    for (int i = 0; i < C; ++i) {
      u16* sCur  = (i & 1) ? splB : splA;
      u16* sNext = (i & 1) ? splA : splB;
      Job jDcnC = {dcnT, sCur, dcn_b, bn1_g, bn1_b, bufA, 1024, i * np, np};
      int n0 = tch * 8;
      int n1 = (i == 0) ? 90 : 0;
      bool hasS = (i + 1 < C);
      int ns = hasS ? 9 * (np / 16) : 0;
      dcn_chunk<1 | 4 | 8, 2><<<dim3(n0 + n1 + ns), blk, 0, stream>>>(
          jDcnC, jCls3, n0, tch, n1,
          featP, offp, sNext, (i + 1) * np, hasS ? np : 16);
    }
    gemm_dual<4 | 8, 4 | 8><<<dim3(90, 8), blk, 0, stream>>>(jReg2, jReg2, 8);
    gemm_dual<2, 2><<<dim3(90, 4), blk, 0, stream>>>(jReg3, jReg3, 4);
  } else {
    // ---- tier 3: serial chunked fallback ----
    gemm_dual<8, 8><<<dim3(90, 8), blk, 0, stream>>>(jCls2, jCls2, 8);
    int tiles = (int)(avail / 2359296);
    if (tiles < 1) tiles = 1;
    if (tiles > 90) tiles = 90;
    for (int t0 = 0; t0 < 90; t0 += tiles) {
      int nt = (90 - t0) < tiles ? (90 - t0) : tiles;
      int pix0 = t0 * 128, npp = nt * 128;
      sample_standalone<<<dim3(nt * 8, 9), blk, 0, stream>>>(featP, offp, spl, pix0, npp);
      Job jDcn = {dcnT, spl, dcn_b, bn1_g, bn1_b, bufA, 1024, pix0, npp};
      gemm_dual<1 | 4 | 8, 1 | 4 | 8><<<dim3(nt, 8), blk, 0, stream>>>(jDcn, jDcn, 8);
    }
    gemm_dual<2, 2><<<dim3(90, 1), blk, 0, stream>>>(jCls3, jCls3, 1);
    gemm_dual<4 | 8, 4 | 8><<<dim3(90, 8), blk, 0, stream>>>(jReg2, jReg2, 8);
    gemm_dual<2, 2><<<dim3(90, 4), blk, 0, stream>>>(jReg3, jReg3, 4);
  }
}